// Round 1
// baseline (64.960 us; speedup 1.0000x reference)
//
#include <hip/hip_runtime.h>

#define BB 512
#define CC 128
#define EPS 1e-6f

// K1: per-row softmax(predicts/T) -> p (ws), plus top-2 scan (stable ties:
// smaller index wins, matching argsort(-p)) and sim_batch scatter-add.
__global__ void softmax_top2_kernel(const float* __restrict__ predicts,
                                    const int* __restrict__ labels,
                                    const float* __restrict__ Tp,
                                    float* __restrict__ p,
                                    float* __restrict__ sim_batch) {
    const int row = blockIdx.x;
    const int tid = threadIdx.x;  // 0..127, one per class
    __shared__ float red[CC];
    __shared__ float sp[CC];

    const float T = Tp[0];
    const float z = predicts[row * CC + tid] / T;

    // max-reduce
    red[tid] = z; __syncthreads();
    for (int s = CC / 2; s > 0; s >>= 1) {
        if (tid < s) red[tid] = fmaxf(red[tid], red[tid + s]);
        __syncthreads();
    }
    const float m = red[0]; __syncthreads();

    const float e = expf(z - m);
    red[tid] = e; __syncthreads();
    for (int s = CC / 2; s > 0; s >>= 1) {
        if (tid < s) red[tid] += red[tid + s];
        __syncthreads();
    }
    const float pv = e / red[0];

    p[row * CC + tid] = pv;
    sp[tid] = pv;
    __syncthreads();

    if (tid == 0) {
        // stable descending argsort semantics: strict > keeps earliest index
        float bv = -1.0f; int bi = 0;
        float sv = -1.0f; int si = 0;
        #pragma unroll 4
        for (int c = 0; c < CC; ++c) {
            const float v = sp[c];
            if (v > bv)      { sv = bv; si = bi; bv = v; bi = c; }
            else if (v > sv) { sv = v;  si = c; }
        }
        const int lbl = labels[row];
        if (bi == lbl) {  // hit: top-1 prediction equals label (C>1 always)
            atomicAdd(&sim_batch[lbl * CC + si], 1.0f);
        }
    }
}

// K2: one block per sample a; threads stride over b>a.
//   same-label pair: IC term = |sum_c pa[c]*log(pa[c]/(pb[c]+eps)+eps)|
//   diff-label pair: ISC term = |(t_la + t_lb) * sim_all[la,lb]|  (onehot
//   difference is nonzero only at c==la and c==lb)
__global__ void pairs_kernel(const float* __restrict__ p,
                             const int* __restrict__ labels,
                             const float* __restrict__ sim_all,
                             const int* __restrict__ epoch_p,
                             double* __restrict__ acc) {
    const int a = blockIdx.x;
    const int tid = threadIdx.x;  // 0..255
    __shared__ float pa[CC];
    __shared__ double sred[256];

    if (tid < CC) pa[tid] = p[a * CC + tid];
    __syncthreads();

    const int la = labels[a];
    const int ep = epoch_p[0];

    double ic = 0.0, isc = 0.0, scnt = 0.0, dcnt = 0.0;

    for (int b = a + 1 + tid; b < BB; b += 256) {
        const int lb = labels[b];
        const float* __restrict__ pb = p + b * CC;
        if (lb == la) {
            double S = 0.0;
            #pragma unroll 4
            for (int c = 0; c < CC; ++c) {
                const float x = pa[c];
                S += (double)(x * logf(x / (pb[c] + EPS) + EPS));
            }
            ic += fabs(S);
            scnt += 1.0;
        } else {
            const float x1 = pa[la];
            const float x2 = pa[lb];
            const float t1 = x1 * logf(x1 / (pb[la] + EPS) + EPS);
            const float t2 = x2 * logf(x2 / (pb[lb] + EPS) + EPS);
            const float sim = (ep == 0) ? 1.0f : sim_all[la * CC + lb];
            isc += fabs((double)((t1 + t2) * sim));
            dcnt += 1.0;
        }
    }

    // 4 sequential block tree-reductions through one shared buffer
    double vals[4] = {ic, isc, scnt, dcnt};
    for (int k = 0; k < 4; ++k) {
        sred[tid] = vals[k]; __syncthreads();
        for (int s = 128; s > 0; s >>= 1) {
            if (tid < s) sred[tid] += sred[tid + s];
            __syncthreads();
        }
        if (tid == 0) atomicAdd(&acc[k], sred[0]);
        __syncthreads();
    }
}

// K3: finalize with the reference's exact guard/reciprocal sequence.
__global__ void finalize_kernel(const double* __restrict__ acc,
                                const float* __restrict__ mu_p,
                                const float* __restrict__ eta_p,
                                float* __restrict__ out) {
    double IC = acc[0], ISC = acc[1];
    const double sc = acc[2], dc = acc[3];
    if (sc != 0.0) IC = IC / sc;
    if (dc != 0.0) ISC = ISC / dc;
    if (ISC != 0.0) ISC = (1.0 / (ISC + (double)EPS)) * (double)mu_p[0];
    IC = IC * (double)eta_p[0];
    out[0] = (float)(IC + ISC);
}

extern "C" void kernel_launch(void* const* d_in, const int* in_sizes, int n_in,
                              void* d_out, int out_size, void* d_ws, size_t ws_size,
                              hipStream_t stream) {
    const float* predicts = (const float*)d_in[0];  // (512,128) f32
    const int*   labels   = (const int*)d_in[1];    // (512,) i32
    const float* sim_all  = (const float*)d_in[2];  // (128,128) f32
    const int*   epoch    = (const int*)d_in[3];    // scalar i32
    const float* T        = (const float*)d_in[4];  // scalar f32
    const float* mu       = (const float*)d_in[5];  // scalar f32
    const float* eta      = (const float*)d_in[6];  // scalar f32

    float* out = (float*)d_out;          // [0]=IC+ISC, [1..16384]=sim_batch (128,128)
    float* p   = (float*)d_ws;           // (512,128) f32 = 256 KB
    double* acc = (double*)((char*)d_ws + BB * CC * sizeof(float));  // 4 doubles

    // zero outputs + accumulators every call (harness doesn't re-poison)
    hipMemsetAsync(d_out, 0, (size_t)out_size * sizeof(float), stream);
    hipMemsetAsync(acc, 0, 4 * sizeof(double), stream);

    softmax_top2_kernel<<<BB, CC, 0, stream>>>(predicts, labels, T, p, out + 1);
    pairs_kernel<<<BB, 256, 0, stream>>>(p, labels, sim_all, epoch, acc);
    finalize_kernel<<<1, 1, 0, stream>>>(acc, mu, eta, out);
}

// Round 2
// 24.602 us; speedup vs baseline: 2.6404x; 2.6404x over previous
//
#include <hip/hip_runtime.h>

#define BB 512
#define CC 128
#define EPS 1e-6f
#define NPAIR (BB * (BB - 1) / 2)  // 130816 = 511 * 256

__device__ __forceinline__ int tri_prefix(int a) {
    // number of pairs (i<j) with i < a:  S(a) = a*(2B-1-a)/2
    return (a * (2 * BB - 1 - a)) >> 1;
}

// ---------------------------------------------------------------------------
// K1: one block per row. softmax(predicts/T), precompute lg=log(p+eps),
// xlg = p*log p (via log p = (z-m) - log(sumexp), one logf/row), H = sum xlg,
// per-row scalars w/xw/lgw at the label column, parallel stable top-2,
// sim_batch scatter-add.
// ---------------------------------------------------------------------------
__global__ __launch_bounds__(CC) void row_kernel(
    const float* __restrict__ predicts, const int* __restrict__ labels,
    const float* __restrict__ Tp,
    float* __restrict__ p, float* __restrict__ lg, float* __restrict__ xlg,
    float* __restrict__ H, float* __restrict__ w, float* __restrict__ xw,
    float* __restrict__ lgw, float* __restrict__ sim_batch) {
    const int row = blockIdx.x;
    const int tid = threadIdx.x;  // 0..127

    __shared__ float red[CC];
    __shared__ float v1[CC], v2[CC];
    __shared__ int   i1[CC], i2[CC];

    const float T = Tp[0];
    const float z = predicts[row * CC + tid] / T;

    // max reduce
    red[tid] = z; __syncthreads();
    for (int s = CC / 2; s > 0; s >>= 1) {
        if (tid < s) red[tid] = fmaxf(red[tid], red[tid + s]);
        __syncthreads();
    }
    const float mx = red[0]; __syncthreads();

    const float e = expf(z - mx);
    red[tid] = e; __syncthreads();
    for (int s = CC / 2; s > 0; s >>= 1) {
        if (tid < s) red[tid] += red[tid + s];
        __syncthreads();
    }
    const float sum = red[0]; __syncthreads();

    const float pv  = e / sum;
    const float lpv = (z - mx) - logf(sum);   // log p, one logf per row
    const float lgv = logf(pv + EPS);
    const float xv  = pv * lpv;

    p[row * CC + tid]   = pv;
    lg[row * CC + tid]  = lgv;
    xlg[row * CC + tid] = xv;

    // H = sum_c xlg
    red[tid] = xv; __syncthreads();
    for (int s = CC / 2; s > 0; s >>= 1) {
        if (tid < s) red[tid] += red[tid + s];
        __syncthreads();
    }
    const int lbl = labels[row];
    if (tid == 0) H[row] = red[0];
    if (tid == lbl) { w[row] = pv; xw[row] = xv; lgw[row] = lgv; }

    // stable top-2 tree reduction (ties -> lower index, matching argsort(-p))
    v1[tid] = pv; i1[tid] = tid; v2[tid] = -1.0f; i2[tid] = CC;
    __syncthreads();
    for (int s = CC / 2; s > 0; s >>= 1) {
        if (tid < s) {
            float Av1 = v1[tid],     Av2 = v2[tid];
            int   Ai1 = i1[tid],     Ai2 = i2[tid];
            float Bv1 = v1[tid + s], Bv2 = v2[tid + s];
            int   Bi1 = i1[tid + s], Bi2 = i2[tid + s];
            bool Bwins = (Bv1 > Av1) || (Bv1 == Av1 && Bi1 < Ai1);
            float n1v, n2v; int n1i, n2i;
            if (Bwins) {
                n1v = Bv1; n1i = Bi1;
                bool g = (Av1 > Bv2) || (Av1 == Bv2 && Ai1 < Bi2);
                n2v = g ? Av1 : Bv2; n2i = g ? Ai1 : Bi2;
            } else {
                n1v = Av1; n1i = Ai1;
                bool g = (Bv1 > Av2) || (Bv1 == Av2 && Bi1 < Ai2);
                n2v = g ? Bv1 : Av2; n2i = g ? Bi1 : Ai2;
            }
            v1[tid] = n1v; i1[tid] = n1i; v2[tid] = n2v; i2[tid] = n2i;
        }
        __syncthreads();
    }
    if (tid == 0 && i1[0] == lbl) {
        atomicAdd(&sim_batch[lbl * CC + i2[0]], 1.0f);
    }
}

// ---------------------------------------------------------------------------
// K2: one thread per pair (exactly 511*256 threads). Diff-label pairs: 3
// scattered loads + arithmetic. Same-label pairs: cooperative wave dot
// product dot(p[a], lg[b]) via ballot + shuffle reduce. Per-block partials.
// ---------------------------------------------------------------------------
__global__ __launch_bounds__(256) void pairs_kernel(
    const float* __restrict__ p, const float* __restrict__ lg,
    const float* __restrict__ xlg, const float* __restrict__ H,
    const float* __restrict__ w, const float* __restrict__ xw,
    const float* __restrict__ lgw, const int* __restrict__ labels,
    const float* __restrict__ sim_all, const int* __restrict__ epoch_p,
    double* __restrict__ partials) {
    const int tid = threadIdx.x;
    const int k = blockIdx.x * 256 + tid;  // 0..130815, all valid

    // triangular decode: largest a with S(a) <= k
    int a = (int)((1023.0 - sqrt(1023.0 * 1023.0 - 8.0 * (double)k)) * 0.5);
    if (a < 0) a = 0;
    while (tri_prefix(a + 1) <= k) ++a;
    while (tri_prefix(a) > k) --a;
    const int b = a + 1 + (k - tri_prefix(a));

    const int la = labels[a], lb = labels[b];
    const bool same = (la == lb);

    double ic = 0.0, isc = 0.0, scnt = 0.0, dcnt = 0.0;

    if (!same) {
        const float t1 = xw[a] - w[a] * lg[b * CC + la];
        const float t2 = xlg[a * CC + lb] - p[a * CC + lb] * lgw[b];
        const float sim = (epoch_p[0] == 0) ? 1.0f : sim_all[la * CC + lb];
        isc = fabsf((t1 + t2) * sim);
        dcnt = 1.0;
    }

    // cooperative same-label dot products
    const int lane = tid & 63;
    unsigned long long m = __ballot(same);
    while (m) {
        const int src = __builtin_ctzll(m);
        m &= m - 1;
        const int aa = __shfl(a, src, 64);
        const int bb = __shfl(b, src, 64);
        float dot = p[aa * CC + lane] * lg[bb * CC + lane] +
                    p[aa * CC + lane + 64] * lg[bb * CC + lane + 64];
        for (int s = 32; s > 0; s >>= 1) dot += __shfl_xor(dot, s, 64);
        if (lane == src) {
            ic = fabs((double)H[aa] - (double)dot);
            scnt = 1.0;
        }
    }

    // per-wave shuffle reduce -> LDS -> one partial row per block
    __shared__ double sred[4][4];  // [wave][quantity]
    double vals[4] = {ic, isc, scnt, dcnt};
    #pragma unroll
    for (int q = 0; q < 4; ++q) {
        double v = vals[q];
        for (int s = 32; s > 0; s >>= 1) v += __shfl_xor(v, s, 64);
        if (lane == 0) sred[tid >> 6][q] = v;
    }
    __syncthreads();
    if (tid < 4) {
        partials[blockIdx.x * 4 + tid] =
            sred[0][tid] + sred[1][tid] + sred[2][tid] + sred[3][tid];
    }
}

// ---------------------------------------------------------------------------
// K3: reduce 511 partial rows, finalize with the reference's guard sequence.
// ---------------------------------------------------------------------------
__global__ __launch_bounds__(256) void finalize_kernel(
    const double* __restrict__ partials, const float* __restrict__ mu_p,
    const float* __restrict__ eta_p, float* __restrict__ out) {
    const int tid = threadIdx.x;
    const int lane = tid & 63;
    double v[4] = {0.0, 0.0, 0.0, 0.0};
    for (int i = tid; i < 511; i += 256) {
        #pragma unroll
        for (int q = 0; q < 4; ++q) v[q] += partials[i * 4 + q];
    }
    __shared__ double sred[4][4];
    #pragma unroll
    for (int q = 0; q < 4; ++q) {
        double x = v[q];
        for (int s = 32; s > 0; s >>= 1) x += __shfl_xor(x, s, 64);
        if (lane == 0) sred[tid >> 6][q] = x;
    }
    __syncthreads();
    if (tid == 0) {
        double IC  = sred[0][0] + sred[1][0] + sred[2][0] + sred[3][0];
        double ISC = sred[0][1] + sred[1][1] + sred[2][1] + sred[3][1];
        double sc  = sred[0][2] + sred[1][2] + sred[2][2] + sred[3][2];
        double dc  = sred[0][3] + sred[1][3] + sred[2][3] + sred[3][3];
        if (sc != 0.0) IC = IC / sc;
        if (dc != 0.0) ISC = ISC / dc;
        if (ISC != 0.0) ISC = (1.0 / (ISC + (double)EPS)) * (double)mu_p[0];
        IC = IC * (double)eta_p[0];
        out[0] = (float)(IC + ISC);
    }
}

extern "C" void kernel_launch(void* const* d_in, const int* in_sizes, int n_in,
                              void* d_out, int out_size, void* d_ws, size_t ws_size,
                              hipStream_t stream) {
    const float* predicts = (const float*)d_in[0];  // (512,128) f32
    const int*   labels   = (const int*)d_in[1];    // (512,) i32
    const float* sim_all  = (const float*)d_in[2];  // (128,128) f32
    const int*   epoch    = (const int*)d_in[3];    // scalar i32
    const float* T        = (const float*)d_in[4];  // scalar f32
    const float* mu       = (const float*)d_in[5];  // scalar f32
    const float* eta      = (const float*)d_in[6];  // scalar f32

    float* out = (float*)d_out;  // [0] = IC+ISC, [1..16384] = sim_batch (128,128)

    // ws layout (floats unless noted)
    float* p    = (float*)d_ws;            // 512*128
    float* lg   = p + BB * CC;             // 512*128
    float* xlg  = lg + BB * CC;            // 512*128
    float* H    = xlg + BB * CC;           // 512
    float* w    = H + BB;                  // 512
    float* xw   = w + BB;                  // 512
    float* lgw  = xw + BB;                 // 512
    double* partials = (double*)(lgw + BB);  // 511*4 doubles (8B-aligned: offset 198656*4)

    // zero the output (sim_batch is atomically accumulated; harness doesn't re-poison)
    hipMemsetAsync(d_out, 0, (size_t)out_size * sizeof(float), stream);

    row_kernel<<<BB, CC, 0, stream>>>(predicts, labels, T, p, lg, xlg, H, w, xw,
                                      lgw, out + 1);
    pairs_kernel<<<NPAIR / 256, 256, 0, stream>>>(p, lg, xlg, H, w, xw, lgw,
                                                  labels, sim_all, epoch, partials);
    finalize_kernel<<<1, 256, 0, stream>>>(partials, mu, eta, out);
}